// Round 10
// baseline (660.099 us; speedup 1.0000x reference)
//
#include <hip/hip_runtime.h>
#include <hip/hip_cooperative_groups.h>

namespace cg = cooperative_groups;

// QueryAndGroupRRI: B=4, N=16384, M=2048, nsample=32, radius=0.1
// Inputs (float32): xyz (4,16384,3), new_xyz (4,2048,3)
// Output (float32): (4, 33, 2048, 32)  [dis_sort rows 0..31, grouped_r row 32]
//
// R10: single cooperative kernel (zero->count->scan->scatter->query, 4 grid
// syncs) kills 4 dispatch gaps; per-column prune + per-column z-window cuts
// ~20% of candidates. Selection/sort/geometry byte-identical to verified R9.
// Fallback: R9 5-dispatch path if cooperative launch unavailable.

#define BB 4
#define NN 16384
#define MM 2048
#define NS 32
#define R2 0.01f
#define GZ 20
#define NCELL 2000
#define CPAD 2048
#define HCAP 128

#define WS_CUR_OFF (32 * 1024)
#define WS_CNT_OFF (64 * 1024)
#define WS_PTS_OFF (96 * 1024)
#define WS_NEED (WS_PTS_OFF + (size_t)BB * NN * 16)

__device__ __forceinline__ int cell_of(float x, float y, float z) {
    int ci = (int)(x * 10.0f); ci = ci < 0 ? 0 : (ci > 9 ? 9 : ci);
    int cj = (int)(y * 10.0f); cj = cj < 0 ? 0 : (cj > 9 ? 9 : cj);
    int ck = (int)(z * 20.0f); ck = ck < 0 ? 0 : (ck > 19 ? 19 : ck);
    return (ci * 10 + cj) * GZ + ck;
}

// ================= shared query body (R9-verified + column pruning) =========
__device__ __forceinline__ void qgr_query_body(
    const float* __restrict__ xyz,
    const float* __restrict__ nxyz,
    const int* __restrict__ offi,
    const float4* __restrict__ pts,
    float* __restrict__ out,
    int bx,
    float4 (*s_hit)[2][HCAP],
    float4 (*s_sel)[2][NS]) {

    const int lane = threadIdx.x & 63;
    const int w = threadIdx.x >> 6;
    const int sub = lane & 31;
    const int half = lane >> 5;
    const int q0 = bx * 8 + w * 2;
    const int b = q0 >> 11;

    const float* xb = xyz + (size_t)b * NN * 3;
    const float* nq = nxyz + (size_t)q0 * 3;
    const float cx0 = nq[0], cy0 = nq[1], cz0 = nq[2];
    const float cx1 = nq[3], cy1 = nq[4], cz1 = nq[5];
    const unsigned long long lmask = (1ull << lane) - 1ull;

    const int* offb = offi + b * CPAD;
    const float4* ptsb = pts + (size_t)b * NN;

    int hits01[2];
    for (int tq = 0; tq < 2; ++tq) {
        const float ccx = tq ? cx1 : cx0;
        const float ccy = tq ? cy1 : cy0;
        const float ccz = tq ? cz1 : cz0;

        int ci0 = (int)(ccx * 10.0f); ci0 = ci0 < 0 ? 0 : (ci0 > 9 ? 9 : ci0);
        int cj0 = (int)(ccy * 10.0f); cj0 = cj0 < 0 ? 0 : (cj0 > 9 ? 9 : cj0);

        int rs[9], rl[9];
        #pragma unroll
        for (int r = 0; r < 9; ++r) { rs[r] = 0; rl[r] = 0; }
        int nr = 0;
        #pragma unroll
        for (int di = -1; di <= 1; ++di) {
            int ii = ci0 + di; if ((unsigned)ii > 9u) continue;
            float xlo = ii * 0.1f, xhi = xlo + 0.1f;
            float dxm = fmaxf(0.f, fmaxf(xlo - ccx, ccx - xhi));
            #pragma unroll
            for (int dj = -1; dj <= 1; ++dj) {
                int jj = cj0 + dj; if ((unsigned)jj > 9u) continue;
                float ylo = jj * 0.1f, yhi = ylo + 0.1f;
                float dym = fmaxf(0.f, fmaxf(ylo - ccy, ccy - yhi));
                float dxy2 = dxm * dxm + dym * dym;
                if (dxy2 >= R2 + 1e-6f) continue;   // provably hit-free column
                float zh = sqrtf(fmaxf(R2 - dxy2, 0.f)) + 1e-3f;
                int zlo = (int)((ccz - zh) * 20.f); if (zlo < 0) zlo = 0;
                int zhi = (int)((ccz + zh) * 20.f); if (zhi > 19) zhi = 19;
                int base2 = (ii * 10 + jj) * GZ;
                int s0 = offb[base2 + zlo];
                int e0 = offb[base2 + zhi + 1];
                int len = e0 - s0;
                if (len > 0) { rs[nr] = s0; rl[nr] = len; ++nr; }
            }
        }

        float4 P[9];
        #pragma unroll
        for (int r = 0; r < 9; ++r) {
            int a = (lane < rl[r]) ? (rs[r] + lane) : 0;
            P[r] = ptsb[a];
        }

        int hits = 0;
        #pragma unroll
        for (int r = 0; r < 9; ++r) {
            float dx = __fsub_rn(ccx, P[r].x);
            float dy = __fsub_rn(ccy, P[r].y);
            float dz = __fsub_rn(ccz, P[r].z);
            float d2 = __fadd_rn(__fadd_rn(__fmul_rn(dx, dx), __fmul_rn(dy, dy)),
                                 __fmul_rn(dz, dz));
            bool hit = (lane < rl[r]) && (d2 < R2);
            unsigned long long bal = __ballot(hit);
            if (bal) {
                int rank = __popcll(bal & lmask);
                int slot = hits + rank;
                if (hit && slot < HCAP) s_hit[w][tq][slot] = P[r];
                hits += __popcll(bal);
            }
        }
        for (int r = 0; r < nr; ++r) {           // rare: ranges > 64
            for (int t0 = 64; t0 < rl[r]; t0 += 64) {
                int t = t0 + lane;
                bool act = t < rl[r];
                float4 Q = ptsb[rs[r] + (act ? t : 0)];
                float dx = __fsub_rn(ccx, Q.x);
                float dy = __fsub_rn(ccy, Q.y);
                float dz = __fsub_rn(ccz, Q.z);
                float d2 = __fadd_rn(__fadd_rn(__fmul_rn(dx, dx), __fmul_rn(dy, dy)),
                                     __fmul_rn(dz, dz));
                bool hit = act && (d2 < R2);
                unsigned long long bal = __ballot(hit);
                if (bal) {
                    int rank = __popcll(bal & lmask);
                    int slot = hits + rank;
                    if (hit && slot < HCAP) s_hit[w][tq][slot] = Q;
                    hits += __popcll(bal);
                }
            }
        }
        hits01[tq] = hits;
    }

    const int hits = half ? hits01[1] : hits01[0];
    const int cap = hits < HCAP ? hits : HCAP;
    const float ccx = half ? cx1 : cx0;
    const float ccy = half ? cy1 : cy0;
    const float ccz = half ? cz1 : cz0;

    // 128-elem selection bitonic in 4 regs x 32 lanes (verified R7-R9)
    int key[4];
    #pragma unroll
    for (int r = 0; r < 4; ++r) {
        int e = r * 32 + sub;
        int idx_e = __float_as_int(s_hit[w][half][e].w);
        key[r] = (e < cap) ? ((idx_e << 8) | e) : 0x7fffffff;
    }
    #pragma unroll
    for (int k = 2; k <= 16; k <<= 1) {
        #pragma unroll
        for (int j = k >> 1; j > 0; j >>= 1) {
            bool lower = (sub & j) == 0;
            bool asc = (sub & k) == 0;
            bool keepmin = (lower == asc);
            #pragma unroll
            for (int r = 0; r < 4; ++r) {
                int p = __shfl_xor(key[r], j);
                key[r] = keepmin ? min(key[r], p) : max(key[r], p);
            }
        }
    }
    #pragma unroll
    for (int j = 16; j > 0; j >>= 1) {
        bool lower = (sub & j) == 0;
        #pragma unroll
        for (int r = 0; r < 4; ++r) {
            int p = __shfl_xor(key[r], j);
            bool asc = (r & 1) == 0;
            key[r] = (lower == asc) ? min(key[r], p) : max(key[r], p);
        }
    }
    {
        int t0 = min(key[0], key[1]); key[1] = max(key[0], key[1]); key[0] = t0;
        int t2 = max(key[2], key[3]); key[3] = min(key[2], key[3]); key[2] = t2;
    }
    #pragma unroll
    for (int j = 16; j > 0; j >>= 1) {
        bool lower = (sub & j) == 0;
        #pragma unroll
        for (int r = 0; r < 4; ++r) {
            int p = __shfl_xor(key[r], j);
            bool asc = (r & 2) == 0;
            key[r] = (lower == asc) ? min(key[r], p) : max(key[r], p);
        }
    }
    {
        int t0 = min(key[0], key[2]); key[2] = max(key[0], key[2]); key[0] = t0;
        int t1 = min(key[1], key[3]); key[3] = max(key[1], key[3]); key[1] = t1;
        t0 = min(key[0], key[1]); key[1] = max(key[0], key[1]); key[0] = t0;
        t1 = min(key[2], key[3]); key[3] = max(key[2], key[3]); key[2] = t1;
    }
    #pragma unroll
    for (int j = 16; j > 0; j >>= 1) {
        bool lower = (sub & j) == 0;
        #pragma unroll
        for (int r = 0; r < 4; ++r) {
            int p = __shfl_xor(key[r], j);
            key[r] = lower ? min(key[r], p) : max(key[r], p);
        }
    }

    const int found = hits < NS ? hits : NS;
    const int hbase = half << 5;
    float4 sel = make_float4(0.f, 0.f, 0.f, 0.f);
    if (sub < found) sel = s_hit[w][half][key[0] & 0xFF];
    float p0x, p0y, p0z;
    if (found == 0) { p0x = xb[0]; p0y = xb[1]; p0z = xb[2]; }
    else {
        p0x = __shfl(sel.x, hbase); p0y = __shfl(sel.y, hbase); p0z = __shfl(sel.z, hbase);
    }
    if (sub >= found) { sel.x = p0x; sel.y = p0y; sel.z = p0z; }
    const float hx = sel.x, hy = sel.y, hz = sel.z;

    s_sel[w][half][sub] = sel;

    float v[NS];
    #pragma unroll
    for (int ii = 0; ii < NS; ++ii) {
        float4 B = s_sel[w][half][ii];
        float dx = __fsub_rn(B.x, hx);
        float dy = __fsub_rn(B.y, hy);
        float dz = __fsub_rn(B.z, hz);
        v[ii] = sqrtf(__fadd_rn(__fadd_rn(__fmul_rn(dx, dx), __fmul_rn(dy, dy)),
                                __fmul_rn(dz, dz)));
    }

    float r8[8];
    #pragma unroll
    for (int t = 0; t < 8; ++t) {
        r8[t] = __fadd_rn(__fadd_rn(__fadd_rn(v[t], v[t + 8]), v[t + 16]), v[t + 24]);
    }
    float mv = __fadd_rn(__fadd_rn(__fadd_rn(r8[0], r8[1]), __fadd_rn(r8[2], r8[3])),
                         __fadd_rn(__fadd_rn(r8[4], r8[5]), __fadd_rn(r8[6], r8[7])));
    int mi = sub;
    #pragma unroll
    for (int off = 1; off < 32; off <<= 1) {
        float ov = __shfl_xor(mv, off);
        int oi = __shfl_xor(mi, off);
        if (ov > mv || (ov == mv && oi < mi)) { mv = ov; mi = oi; }
    }

    float4 T = s_sel[w][half][mi];
    const float tx = T.x, ty = T.y, tz = T.z;

    float ux = ccy * tz - ccz * ty, uy = ccz * tx - ccx * tz, uz = ccx * ty - ccy * tx;
    float vx = uy * ccz - uz * ccy, vy = uz * ccx - ux * ccz, vz = ux * ccy - uy * ccx;
    float vn = fmaxf(sqrtf(vx * vx + vy * vy + vz * vz), 1e-37f);
    float tnx = vx / vn, tny = vy / vn, tnz = vz / vn;

    float nrm = sqrtf(ccx * ccx + ccy * ccy + ccz * ccz);
    float dn = nrm + 1e-8f;
    float nnx = ccx / dn, nny = ccy / dn, nnz = ccz / dn;

    float ax = ccy * hz - ccz * hy, ay = ccz * hx - ccx * hz, az = ccx * hy - ccy * hx;
    float px = ay * ccz - az * ccy, py = az * ccx - ax * ccz, pz = ax * ccy - ay * ccx;
    float pn = fmaxf(sqrtf(px * px + py * py + pz * pz), 1e-37f);
    px /= pn; py /= pn; pz /= pn;

    float qx = py * tnz - pz * tny;
    float qy = pz * tnx - px * tnz;
    float qz = px * tny - py * tnx;
    float sinv = qx * nnx + qy * nny + qz * nnz;

    float gr = sqrtf(hx * hx + hy * hy + hz * hz);

    const int m_h = (q0 + half) & (MM - 1);
    const size_t rowstride = (size_t)MM * NS;
    const size_t obase = (((size_t)b * 33) * MM + m_h) * NS + sub;
    out[obase + 32 * rowstride] = gr;

    // Batcher odd-even mergesort (verified R8/R9)
    #pragma unroll
    for (int p = 1; p < NS; p <<= 1) {
        #pragma unroll
        for (int k = p; k >= 1; k >>= 1) {
            #pragma unroll
            for (int j = k & (p - 1); j + k < NS; j += 2 * k) {
                #pragma unroll
                for (int i = 0; i < k; ++i) {
                    if (i + j + k < NS) {
                        int x = i + j, y = i + j + k;
                        if ((x / (2 * p)) == (y / (2 * p))) {
                            float lo = fminf(v[x], v[y]);
                            v[y] = fmaxf(v[x], v[y]);
                            v[x] = lo;
                        }
                    }
                }
            }
        }
    }

    #pragma unroll
    for (int ii = 0; ii < NS; ++ii)
        out[obase + (size_t)ii * rowstride] = v[ii] * sinv;
}

// ================= build phase helpers ======================================
__device__ __forceinline__ void d_scan_block(int b, int t, const int* cnt,
                                             int* off, int* cur, int* wsum) {
    // 256 threads, 8 cells each, contiguous
    int base = b * CPAD + t * 8;
    int c[8]; int s = 0;
    #pragma unroll
    for (int k = 0; k < 8; ++k) { c[k] = cnt[base + k]; s += c[k]; }
    int lane = t & 63, wid = t >> 6;
    int x = s;
    #pragma unroll
    for (int o = 1; o < 64; o <<= 1) {
        int u = __shfl_up(x, o);
        if (lane >= o) x += u;
    }
    if (lane == 63) wsum[wid] = x;
    __syncthreads();
    int pre = 0;
    #pragma unroll
    for (int i2 = 0; i2 < 4; ++i2) pre += (i2 < wid) ? wsum[i2] : 0;
    int excl = x + pre - s;
    #pragma unroll
    for (int k = 0; k < 8; ++k) {
        off[base + k] = excl; cur[base + k] = excl; excl += c[k];
    }
}

// ================= cooperative fused kernel =================================
__global__ __launch_bounds__(256) void k_coop(
    const float* __restrict__ xyz, const float* __restrict__ nxyz,
    int* __restrict__ off, int* __restrict__ cur, int* __restrict__ cnt,
    float4* __restrict__ pts, float* __restrict__ out) {

    cg::grid_group g = cg::this_grid();
    const int gtid = blockIdx.x * 256 + threadIdx.x;   // 0..262143

    // A: zero counters
    if (gtid < BB * CPAD) cnt[gtid] = 0;
    g.sync();

    // B: count (cache point in regs)
    float px_ = 0.f, py_ = 0.f, pz_ = 0.f; int cellb = 0, bi = 0, pidx = 0;
    if (gtid < BB * NN) {
        bi = gtid >> 14; pidx = gtid & (NN - 1);
        const float* p = xyz + (size_t)gtid * 3;
        px_ = p[0]; py_ = p[1]; pz_ = p[2];
        cellb = bi * CPAD + cell_of(px_, py_, pz_);
        atomicAdd(&cnt[cellb], 1);
    }
    __threadfence();
    g.sync();

    // C: scan (blocks 0..3)
    __shared__ int wsum4[4];
    if (blockIdx.x < BB) d_scan_block(blockIdx.x, threadIdx.x, cnt, off, cur, wsum4);
    __threadfence();
    g.sync();

    // D: scatter
    if (gtid < BB * NN) {
        int pos = atomicAdd(&cur[cellb], 1);
        pts[(size_t)bi * NN + pos] = make_float4(px_, py_, pz_, __int_as_float(pidx));
    }
    __threadfence();
    g.sync();

    // E: query
    __shared__ float4 s_hit[4][2][HCAP];
    __shared__ float4 s_sel[4][2][NS];
    qgr_query_body(xyz, nxyz, off, pts, out, blockIdx.x, s_hit, s_sel);
}

// ================= fallback kernels (R9-verified) ===========================
__global__ __launch_bounds__(256) void k_count(const float* __restrict__ xyz,
                                               int* __restrict__ cnt) {
    int i = blockIdx.x * 256 + threadIdx.x;
    int b = i >> 14;
    const float* p = xyz + (size_t)i * 3;
    atomicAdd(&cnt[b * CPAD + cell_of(p[0], p[1], p[2])], 1);
}

__global__ __launch_bounds__(256) void k_scan(const int* __restrict__ cnt,
                                              int* __restrict__ off,
                                              int* __restrict__ cur) {
    __shared__ int wsum4[4];
    d_scan_block(blockIdx.x, threadIdx.x, cnt, off, cur, wsum4);
}

__global__ __launch_bounds__(256) void k_scatter(const float* __restrict__ xyz,
                                                 int* __restrict__ cur,
                                                 float4* __restrict__ pts) {
    int i = blockIdx.x * 256 + threadIdx.x;
    int b = i >> 14;
    const float* p = xyz + (size_t)i * 3;
    float x = p[0], y = p[1], z = p[2];
    int pos = atomicAdd(&cur[b * CPAD + cell_of(x, y, z)], 1);
    pts[(size_t)b * NN + pos] = make_float4(x, y, z, __int_as_float(i & (NN - 1)));
}

__global__ __launch_bounds__(256) void qgr_grid_kernel(
    const float* __restrict__ xyz, const float* __restrict__ nxyz,
    const int* __restrict__ offi, const float4* __restrict__ pts,
    float* __restrict__ out) {
    __shared__ float4 s_hit[4][2][HCAP];
    __shared__ float4 s_sel[4][2][NS];
    qgr_query_body(xyz, nxyz, offi, pts, out, blockIdx.x, s_hit, s_sel);
}

// ---------------- brute-force fallback (R4-verified, ws too small) ----------
#define CHUNKS 4
__global__ __launch_bounds__(256) void qgr_kernel(
    const float* __restrict__ xyz,
    const float* __restrict__ nxyz,
    float* __restrict__ out) {

    __shared__ float s_gx[4][NS], s_gy[4][NS], s_gz[4][NS];
    __shared__ float s_dis[4][NS][NS + 1];

    const int lane = threadIdx.x & 63;
    const int w = threadIdx.x >> 6;
    const int q = blockIdx.x * 4 + w;
    const int b = q >> 11;
    const int m = q & (MM - 1);

    const float* xb = xyz + (size_t)b * NN * 3;
    const float* nq = nxyz + (size_t)q * 3;
    const float cx = nq[0], cy = nq[1], cz = nq[2];
    const unsigned long long lmask = (1ull << lane) - 1ull;

    int cnt = 0;
    for (int base = 0; base < NN; base += 64 * CHUNKS) {
        float X[CHUNKS], Y[CHUNKS], Z[CHUNKS];
        #pragma unroll
        for (int c = 0; c < CHUNKS; ++c) {
            const float* p = xb + (size_t)(base + c * 64 + lane) * 3;
            X[c] = p[0]; Y[c] = p[1]; Z[c] = p[2];
        }
        bool in[CHUNKS];
        #pragma unroll
        for (int c = 0; c < CHUNKS; ++c) {
            float dx = __fsub_rn(cx, X[c]);
            float dy = __fsub_rn(cy, Y[c]);
            float dz = __fsub_rn(cz, Z[c]);
            float d2 = __fadd_rn(__fadd_rn(__fmul_rn(dx, dx), __fmul_rn(dy, dy)),
                                 __fmul_rn(dz, dz));
            in[c] = d2 < R2;
        }
        #pragma unroll
        for (int c = 0; c < CHUNKS; ++c) {
            unsigned long long bal = __ballot(in[c]);
            if (bal) {
                int rank = __popcll(bal & lmask);
                int slot = cnt + rank;
                if (in[c] && slot < NS) {
                    s_gx[w][slot] = X[c]; s_gy[w][slot] = Y[c]; s_gz[w][slot] = Z[c];
                }
                cnt += __popcll(bal);
            }
        }
        if (cnt >= NS) break;
    }
    __syncthreads();

    int found = cnt < NS ? cnt : NS;
    float p0x, p0y, p0z;
    if (found == 0) { p0x = xb[0]; p0y = xb[1]; p0z = xb[2]; }
    else            { p0x = s_gx[w][0]; p0y = s_gy[w][0]; p0z = s_gz[w][0]; }
    if (lane < NS && lane >= found) {
        s_gx[w][lane] = p0x; s_gy[w][lane] = p0y; s_gz[w][lane] = p0z;
    }
    __syncthreads();

    #pragma unroll
    for (int t = 0; t < 16; ++t) {
        int e = t * 64 + lane;
        int di = e >> 5, dj = e & 31;
        float dx = __fsub_rn(s_gx[w][di], s_gx[w][dj]);
        float dy = __fsub_rn(s_gy[w][di], s_gy[w][dj]);
        float dz = __fsub_rn(s_gz[w][di], s_gz[w][dj]);
        s_dis[w][di][dj] =
            sqrtf(__fadd_rn(__fadd_rn(__fmul_rn(dx, dx), __fmul_rn(dy, dy)), __fmul_rn(dz, dz)));
    }
    __syncthreads();

    {
        int i = lane & 31;
        float r[8];
        #pragma unroll
        for (int t = 0; t < 8; ++t) {
            r[t] = __fadd_rn(__fadd_rn(__fadd_rn(s_dis[w][i][t], s_dis[w][i][t + 8]),
                                        s_dis[w][i][t + 16]),
                             s_dis[w][i][t + 24]);
        }
        float mv = __fadd_rn(__fadd_rn(__fadd_rn(r[0], r[1]), __fadd_rn(r[2], r[3])),
                             __fadd_rn(__fadd_rn(r[4], r[5]), __fadd_rn(r[6], r[7])));
        int mi = i;
        #pragma unroll
        for (int off = 1; off < 64; off <<= 1) {
            float ov = __shfl_xor(mv, off);
            int oi = __shfl_xor(mi, off);
            if (ov > mv || (ov == mv && oi < mi)) { mv = ov; mi = oi; }
        }
        float tx = s_gx[w][mi], ty = s_gy[w][mi], tz = s_gz[w][mi];
        float ux = cy * tz - cz * ty, uy = cz * tx - cx * tz, uz = cx * ty - cy * tx;
        float vx = uy * cz - uz * cy, vy = uz * cx - ux * cz, vz = ux * cy - uy * cx;
        float vn = fmaxf(sqrtf(vx * vx + vy * vy + vz * vz), 1e-37f);
        float tnx = vx / vn, tny = vy / vn, tnz = vz / vn;
        float nr = sqrtf(cx * cx + cy * cy + cz * cz);
        float dn = nr + 1e-8f;
        float nnx = cx / dn, nny = cy / dn, nnz = cz / dn;
        int j = lane & 31;
        float gx = s_gx[w][j], gy = s_gy[w][j], gz = s_gz[w][j];
        float ax = cy * gz - cz * gy, ay = cz * gx - cx * gz, az = cx * gy - cy * gx;
        float px = ay * cz - az * cy, py = az * cx - ax * cz, pz = ax * cy - ay * cx;
        float pn = fmaxf(sqrtf(px * px + py * py + pz * pz), 1e-37f);
        px /= pn; py /= pn; pz /= pn;
        float qx = py * tnz - pz * tny;
        float qy = pz * tnx - px * tnz;
        float qz = px * tny - py * tnx;
        float sinv = qx * nnx + qy * nny + qz * nnz;
        float gr = sqrtf(gx * gx + gy * gy + gz * gz);
        const size_t rowstride = (size_t)MM * NS;
        const size_t obase = (((size_t)b * 33) * MM + m) * NS + j;
        if (lane < NS) out[obase + 32 * rowstride] = gr;
        float v[NS];
        #pragma unroll
        for (int ii = 0; ii < NS; ++ii) v[ii] = s_dis[w][ii][j];
        #pragma unroll
        for (int k = 2; k <= NS; k <<= 1) {
            #pragma unroll
            for (int jj = k >> 1; jj > 0; jj >>= 1) {
                #pragma unroll
                for (int ii = 0; ii < NS; ++ii) {
                    int ll = ii ^ jj;
                    if (ll > ii) {
                        bool up = ((ii & k) == 0);
                        float a = v[ii], c2 = v[ll];
                        bool sw = up ? (a > c2) : (a < c2);
                        if (sw) { v[ii] = c2; v[ll] = a; }
                    }
                }
            }
        }
        if (lane < NS) {
            #pragma unroll
            for (int ii = 0; ii < NS; ++ii)
                out[obase + (size_t)ii * rowstride] = v[ii] * sinv;
        }
    }
}

extern "C" void kernel_launch(void* const* d_in, const int* in_sizes, int n_in,
                              void* d_out, int out_size, void* d_ws, size_t ws_size,
                              hipStream_t stream) {
    (void)in_sizes; (void)n_in; (void)out_size;
    const float* xyz = (const float*)d_in[0];
    const float* nxyz = (const float*)d_in[1];
    float* out = (float*)d_out;

    if (d_ws != nullptr && ws_size >= WS_NEED) {
        char* ws = (char*)d_ws;
        int* off = (int*)ws;
        int* cur = (int*)(ws + WS_CUR_OFF);
        int* cnt = (int*)(ws + WS_CNT_OFF);
        float4* pts = (float4*)(ws + WS_PTS_OFF);

        // try cooperative fused path (host-side attribute query is capture-safe)
        int dev = 0, coop = 0;
        hipGetDevice(&dev);
        hipDeviceGetAttribute(&coop, hipDeviceAttributeCooperativeLaunch, dev);
        bool done = false;
        if (coop) {
            void* args[] = { (void*)&xyz, (void*)&nxyz, (void*)&off, (void*)&cur,
                             (void*)&cnt, (void*)&pts, (void*)&out };
            hipError_t st = hipLaunchCooperativeKernel(
                reinterpret_cast<const void*>(k_coop),
                dim3((BB * MM) / 8), dim3(256), args, 0, stream);
            done = (st == hipSuccess);
            if (!done) (void)hipGetLastError();  // clear sticky error
        }
        if (!done) {
            hipMemsetAsync(cnt, 0, 32 * 1024, stream);
            k_count<<<(BB * NN) / 256, 256, 0, stream>>>(xyz, cnt);
            k_scan<<<BB, 256, 0, stream>>>(cnt, off, cur);
            k_scatter<<<(BB * NN) / 256, 256, 0, stream>>>(xyz, cur, pts);
            qgr_grid_kernel<<<(BB * MM) / 8, 256, 0, stream>>>(xyz, nxyz, off, pts, out);
        }
    } else {
        qgr_kernel<<<(BB * MM) / 4, 256, 0, stream>>>(xyz, nxyz, out);
    }
}

// Round 11
// 115.101 us; speedup vs baseline: 5.7349x; 5.7349x over previous
//
#include <hip/hip_runtime.h>

// QueryAndGroupRRI: B=4, N=16384, M=2048, nsample=32, radius=0.1
// Inputs (float32): xyz (4,16384,3), new_xyz (4,2048,3)
// Output (float32): (4, 33, 2048, 32)  [dis_sort rows 0..31, grouped_r row 32]
//
// R11: revert cooperative kernel (grid.sync ~150us/sync on gfx950 - R10).
// R9 5-dispatch structure + verified column pruning (R10) + merged 18-range
// batched first-round loads (one latency exposure for both queries).

#define BB 4
#define NN 16384
#define MM 2048
#define NS 32
#define R2 0.01f
#define GZ 20
#define NCELL 2000
#define CPAD 2048
#define HCAP 128

#define WS_CUR_OFF (32 * 1024)
#define WS_CNT_OFF (64 * 1024)
#define WS_PTS_OFF (96 * 1024)
#define WS_NEED (WS_PTS_OFF + (size_t)BB * NN * 16)

__device__ __forceinline__ int cell_of(float x, float y, float z) {
    int ci = (int)(x * 10.0f); ci = ci < 0 ? 0 : (ci > 9 ? 9 : ci);
    int cj = (int)(y * 10.0f); cj = cj < 0 ? 0 : (cj > 9 ? 9 : cj);
    int ck = (int)(z * 20.0f); ck = ck < 0 ? 0 : (ck > 19 ? 19 : ck);
    return (ci * 10 + cj) * GZ + ck;
}

// ---- build kernels (R9-verified) ----
__global__ __launch_bounds__(256) void k_count(const float* __restrict__ xyz,
                                               int* __restrict__ cnt) {
    int i = blockIdx.x * 256 + threadIdx.x;
    int b = i >> 14;
    const float* p = xyz + (size_t)i * 3;
    atomicAdd(&cnt[b * CPAD + cell_of(p[0], p[1], p[2])], 1);
}

__global__ __launch_bounds__(256) void k_scan(const int* __restrict__ cnt,
                                              int* __restrict__ off,
                                              int* __restrict__ cur) {
    __shared__ int wsum[4];
    const int b = blockIdx.x, t = threadIdx.x;
    int base = b * CPAD + t * 8;
    int c[8]; int s = 0;
    #pragma unroll
    for (int k = 0; k < 8; ++k) { c[k] = cnt[base + k]; s += c[k]; }
    int lane = t & 63, wid = t >> 6;
    int x = s;
    #pragma unroll
    for (int o = 1; o < 64; o <<= 1) {
        int u = __shfl_up(x, o);
        if (lane >= o) x += u;
    }
    if (lane == 63) wsum[wid] = x;
    __syncthreads();
    int pre = 0;
    #pragma unroll
    for (int i2 = 0; i2 < 4; ++i2) pre += (i2 < wid) ? wsum[i2] : 0;
    int excl = x + pre - s;
    #pragma unroll
    for (int k = 0; k < 8; ++k) {
        off[base + k] = excl; cur[base + k] = excl; excl += c[k];
    }
}

__global__ __launch_bounds__(256) void k_scatter(const float* __restrict__ xyz,
                                                 int* __restrict__ cur,
                                                 float4* __restrict__ pts) {
    int i = blockIdx.x * 256 + threadIdx.x;
    int b = i >> 14;
    const float* p = xyz + (size_t)i * 3;
    float x = p[0], y = p[1], z = p[2];
    int pos = atomicAdd(&cur[b * CPAD + cell_of(x, y, z)], 1);
    pts[(size_t)b * NN + pos] = make_float4(x, y, z, __int_as_float(i & (NN - 1)));
}

// ---- query kernel: R9 body + verified pruning + merged batched loads ----
__global__ __launch_bounds__(256) void qgr_grid_kernel(
    const float* __restrict__ xyz,
    const float* __restrict__ nxyz,
    const int* __restrict__ offi,
    const float4* __restrict__ pts,
    float* __restrict__ out) {

    __shared__ float4 s_hit[4][2][HCAP];   // 16 KB
    __shared__ float4 s_sel[4][2][NS];     // 4 KB

    const int lane = threadIdx.x & 63;
    const int w = threadIdx.x >> 6;
    const int sub = lane & 31;
    const int half = lane >> 5;
    const int q0 = blockIdx.x * 8 + w * 2;
    const int b = q0 >> 11;

    const float* xb = xyz + (size_t)b * NN * 3;
    const float* nq = nxyz + (size_t)q0 * 3;
    const float cx0 = nq[0], cy0 = nq[1], cz0 = nq[2];
    const float cx1 = nq[3], cy1 = nq[4], cz1 = nq[5];
    const unsigned long long lmask = (1ull << lane) - 1ull;

    const int* offb = offi + b * CPAD;
    const float4* ptsb = pts + (size_t)b * NN;

    // ---- phase 1a: ranges for BOTH queries (wave-uniform, mostly SGPR) ----
    int rs[2][9], rl[2][9], nr[2];
    #pragma unroll
    for (int tq = 0; tq < 2; ++tq) {
        const float ccx = tq ? cx1 : cx0;
        const float ccy = tq ? cy1 : cy0;
        const float ccz = tq ? cz1 : cz0;
        int ci0 = (int)(ccx * 10.0f); ci0 = ci0 < 0 ? 0 : (ci0 > 9 ? 9 : ci0);
        int cj0 = (int)(ccy * 10.0f); cj0 = cj0 < 0 ? 0 : (cj0 > 9 ? 9 : cj0);
        #pragma unroll
        for (int r = 0; r < 9; ++r) { rs[tq][r] = 0; rl[tq][r] = 0; }
        int n = 0;
        #pragma unroll
        for (int di = -1; di <= 1; ++di) {
            int ii = ci0 + di; if ((unsigned)ii > 9u) continue;
            float xlo = ii * 0.1f, xhi = xlo + 0.1f;
            float dxm = fmaxf(0.f, fmaxf(xlo - ccx, ccx - xhi));
            #pragma unroll
            for (int dj = -1; dj <= 1; ++dj) {
                int jj = cj0 + dj; if ((unsigned)jj > 9u) continue;
                float ylo = jj * 0.1f, yhi = ylo + 0.1f;
                float dym = fmaxf(0.f, fmaxf(ylo - ccy, ccy - yhi));
                float dxy2 = dxm * dxm + dym * dym;
                if (dxy2 >= R2 + 1e-6f) continue;   // provably hit-free column
                float zh = sqrtf(fmaxf(R2 - dxy2, 0.f)) + 1e-3f;
                int zlo = (int)((ccz - zh) * 20.f); if (zlo < 0) zlo = 0;
                int zhi = (int)((ccz + zh) * 20.f); if (zhi > 19) zhi = 19;
                int base2 = (ii * 10 + jj) * GZ;
                int s0 = offb[base2 + zlo];
                int e0 = offb[base2 + zhi + 1];
                int len = e0 - s0;
                if (len > 0) { rs[tq][n] = s0; rl[tq][n] = len; ++n; }
            }
        }
        nr[tq] = n;
    }

    // ---- phase 1b: ALL 18 first-round loads issued up front ----
    float4 P[2][9];
    #pragma unroll
    for (int tq = 0; tq < 2; ++tq) {
        #pragma unroll
        for (int r = 0; r < 9; ++r) {
            int a = (lane < rl[tq][r]) ? (rs[tq][r] + lane) : 0;
            P[tq][r] = ptsb[a];
        }
    }

    // ---- phase 1c: ballot-append per query, in order ----
    int hits01[2];
    #pragma unroll
    for (int tq = 0; tq < 2; ++tq) {
        const float ccx = tq ? cx1 : cx0;
        const float ccy = tq ? cy1 : cy0;
        const float ccz = tq ? cz1 : cz0;
        int hits = 0;
        #pragma unroll
        for (int r = 0; r < 9; ++r) {
            float dx = __fsub_rn(ccx, P[tq][r].x);
            float dy = __fsub_rn(ccy, P[tq][r].y);
            float dz = __fsub_rn(ccz, P[tq][r].z);
            float d2 = __fadd_rn(__fadd_rn(__fmul_rn(dx, dx), __fmul_rn(dy, dy)),
                                 __fmul_rn(dz, dz));
            bool hit = (lane < rl[tq][r]) && (d2 < R2);
            unsigned long long bal = __ballot(hit);
            if (bal) {
                int rank = __popcll(bal & lmask);
                int slot = hits + rank;
                if (hit && slot < HCAP) s_hit[w][tq][slot] = P[tq][r];
                hits += __popcll(bal);
            }
        }
        for (int r = 0; r < nr[tq]; ++r) {       // rare: ranges > 64
            for (int t0 = 64; t0 < rl[tq][r]; t0 += 64) {
                int t = t0 + lane;
                bool act = t < rl[tq][r];
                float4 Q = ptsb[rs[tq][r] + (act ? t : 0)];
                float dx = __fsub_rn(ccx, Q.x);
                float dy = __fsub_rn(ccy, Q.y);
                float dz = __fsub_rn(ccz, Q.z);
                float d2 = __fadd_rn(__fadd_rn(__fmul_rn(dx, dx), __fmul_rn(dy, dy)),
                                     __fmul_rn(dz, dz));
                bool hit = act && (d2 < R2);
                unsigned long long bal = __ballot(hit);
                if (bal) {
                    int rank = __popcll(bal & lmask);
                    int slot = hits + rank;
                    if (hit && slot < HCAP) s_hit[w][tq][slot] = Q;
                    hits += __popcll(bal);
                }
            }
        }
        hits01[tq] = hits;
    }

    // ---- phase 2: each 32-lane half handles its own query (R9-verified) ----
    const int hits = half ? hits01[1] : hits01[0];
    const int cap = hits < HCAP ? hits : HCAP;
    const float ccx = half ? cx1 : cx0;
    const float ccy = half ? cy1 : cy0;
    const float ccz = half ? cz1 : cz0;

    int key[4];
    #pragma unroll
    for (int r = 0; r < 4; ++r) {
        int e = r * 32 + sub;
        int idx_e = __float_as_int(s_hit[w][half][e].w);
        key[r] = (e < cap) ? ((idx_e << 8) | e) : 0x7fffffff;
    }
    #pragma unroll
    for (int k = 2; k <= 16; k <<= 1) {
        #pragma unroll
        for (int j = k >> 1; j > 0; j >>= 1) {
            bool lower = (sub & j) == 0;
            bool asc = (sub & k) == 0;
            bool keepmin = (lower == asc);
            #pragma unroll
            for (int r = 0; r < 4; ++r) {
                int p = __shfl_xor(key[r], j);
                key[r] = keepmin ? min(key[r], p) : max(key[r], p);
            }
        }
    }
    #pragma unroll
    for (int j = 16; j > 0; j >>= 1) {
        bool lower = (sub & j) == 0;
        #pragma unroll
        for (int r = 0; r < 4; ++r) {
            int p = __shfl_xor(key[r], j);
            bool asc = (r & 1) == 0;
            key[r] = (lower == asc) ? min(key[r], p) : max(key[r], p);
        }
    }
    {
        int t0 = min(key[0], key[1]); key[1] = max(key[0], key[1]); key[0] = t0;
        int t2 = max(key[2], key[3]); key[3] = min(key[2], key[3]); key[2] = t2;
    }
    #pragma unroll
    for (int j = 16; j > 0; j >>= 1) {
        bool lower = (sub & j) == 0;
        #pragma unroll
        for (int r = 0; r < 4; ++r) {
            int p = __shfl_xor(key[r], j);
            bool asc = (r & 2) == 0;
            key[r] = (lower == asc) ? min(key[r], p) : max(key[r], p);
        }
    }
    {
        int t0 = min(key[0], key[2]); key[2] = max(key[0], key[2]); key[0] = t0;
        int t1 = min(key[1], key[3]); key[3] = max(key[1], key[3]); key[1] = t1;
        t0 = min(key[0], key[1]); key[1] = max(key[0], key[1]); key[0] = t0;
        t1 = min(key[2], key[3]); key[3] = max(key[2], key[3]); key[2] = t1;
    }
    #pragma unroll
    for (int j = 16; j > 0; j >>= 1) {
        bool lower = (sub & j) == 0;
        #pragma unroll
        for (int r = 0; r < 4; ++r) {
            int p = __shfl_xor(key[r], j);
            key[r] = lower ? min(key[r], p) : max(key[r], p);
        }
    }

    const int found = hits < NS ? hits : NS;
    const int hbase = half << 5;
    float4 sel = make_float4(0.f, 0.f, 0.f, 0.f);
    if (sub < found) sel = s_hit[w][half][key[0] & 0xFF];
    float p0x, p0y, p0z;
    if (found == 0) { p0x = xb[0]; p0y = xb[1]; p0z = xb[2]; }
    else {
        p0x = __shfl(sel.x, hbase); p0y = __shfl(sel.y, hbase); p0z = __shfl(sel.z, hbase);
    }
    if (sub >= found) { sel.x = p0x; sel.y = p0y; sel.z = p0z; }
    const float hx = sel.x, hy = sel.y, hz = sel.z;

    s_sel[w][half][sub] = sel;

    float v[NS];
    #pragma unroll
    for (int ii = 0; ii < NS; ++ii) {
        float4 B = s_sel[w][half][ii];
        float dx = __fsub_rn(B.x, hx);
        float dy = __fsub_rn(B.y, hy);
        float dz = __fsub_rn(B.z, hz);
        v[ii] = sqrtf(__fadd_rn(__fadd_rn(__fmul_rn(dx, dx), __fmul_rn(dy, dy)),
                                __fmul_rn(dz, dz)));
    }

    float r8[8];
    #pragma unroll
    for (int t = 0; t < 8; ++t) {
        r8[t] = __fadd_rn(__fadd_rn(__fadd_rn(v[t], v[t + 8]), v[t + 16]), v[t + 24]);
    }
    float mv = __fadd_rn(__fadd_rn(__fadd_rn(r8[0], r8[1]), __fadd_rn(r8[2], r8[3])),
                         __fadd_rn(__fadd_rn(r8[4], r8[5]), __fadd_rn(r8[6], r8[7])));
    int mi = sub;
    #pragma unroll
    for (int off = 1; off < 32; off <<= 1) {
        float ov = __shfl_xor(mv, off);
        int oi = __shfl_xor(mi, off);
        if (ov > mv || (ov == mv && oi < mi)) { mv = ov; mi = oi; }
    }

    float4 T = s_sel[w][half][mi];
    const float tx = T.x, ty = T.y, tz = T.z;

    float ux = ccy * tz - ccz * ty, uy = ccz * tx - ccx * tz, uz = ccx * ty - ccy * tx;
    float vx = uy * ccz - uz * ccy, vy = uz * ccx - ux * ccz, vz = ux * ccy - uy * ccx;
    float vn = fmaxf(sqrtf(vx * vx + vy * vy + vz * vz), 1e-37f);
    float tnx = vx / vn, tny = vy / vn, tnz = vz / vn;

    float nrm = sqrtf(ccx * ccx + ccy * ccy + ccz * ccz);
    float dn = nrm + 1e-8f;
    float nnx = ccx / dn, nny = ccy / dn, nnz = ccz / dn;

    float ax = ccy * hz - ccz * hy, ay = ccz * hx - ccx * hz, az = ccx * hy - ccy * hx;
    float px = ay * ccz - az * ccy, py = az * ccx - ax * ccz, pz = ax * ccy - ay * ccx;
    float pn = fmaxf(sqrtf(px * px + py * py + pz * pz), 1e-37f);
    px /= pn; py /= pn; pz /= pn;

    float qx = py * tnz - pz * tny;
    float qy = pz * tnx - px * tnz;
    float qz = px * tny - py * tnx;
    float sinv = qx * nnx + qy * nny + qz * nnz;

    float gr = sqrtf(hx * hx + hy * hy + hz * hz);

    const int m_h = (q0 + half) & (MM - 1);
    const size_t rowstride = (size_t)MM * NS;
    const size_t obase = (((size_t)b * 33) * MM + m_h) * NS + sub;
    out[obase + 32 * rowstride] = gr;

    // Batcher odd-even mergesort (verified R8-R10)
    #pragma unroll
    for (int p = 1; p < NS; p <<= 1) {
        #pragma unroll
        for (int k = p; k >= 1; k >>= 1) {
            #pragma unroll
            for (int j = k & (p - 1); j + k < NS; j += 2 * k) {
                #pragma unroll
                for (int i = 0; i < k; ++i) {
                    if (i + j + k < NS) {
                        int x = i + j, y = i + j + k;
                        if ((x / (2 * p)) == (y / (2 * p))) {
                            float lo = fminf(v[x], v[y]);
                            v[y] = fmaxf(v[x], v[y]);
                            v[x] = lo;
                        }
                    }
                }
            }
        }
    }

    #pragma unroll
    for (int ii = 0; ii < NS; ++ii)
        out[obase + (size_t)ii * rowstride] = v[ii] * sinv;
}

// ---------------- brute-force fallback (R4-verified, ws too small) ----------
#define CHUNKS 4
__global__ __launch_bounds__(256) void qgr_kernel(
    const float* __restrict__ xyz,
    const float* __restrict__ nxyz,
    float* __restrict__ out) {

    __shared__ float s_gx[4][NS], s_gy[4][NS], s_gz[4][NS];
    __shared__ float s_dis[4][NS][NS + 1];

    const int lane = threadIdx.x & 63;
    const int w = threadIdx.x >> 6;
    const int q = blockIdx.x * 4 + w;
    const int b = q >> 11;
    const int m = q & (MM - 1);

    const float* xb = xyz + (size_t)b * NN * 3;
    const float* nq = nxyz + (size_t)q * 3;
    const float cx = nq[0], cy = nq[1], cz = nq[2];
    const unsigned long long lmask = (1ull << lane) - 1ull;

    int cnt = 0;
    for (int base = 0; base < NN; base += 64 * CHUNKS) {
        float X[CHUNKS], Y[CHUNKS], Z[CHUNKS];
        #pragma unroll
        for (int c = 0; c < CHUNKS; ++c) {
            const float* p = xb + (size_t)(base + c * 64 + lane) * 3;
            X[c] = p[0]; Y[c] = p[1]; Z[c] = p[2];
        }
        bool in[CHUNKS];
        #pragma unroll
        for (int c = 0; c < CHUNKS; ++c) {
            float dx = __fsub_rn(cx, X[c]);
            float dy = __fsub_rn(cy, Y[c]);
            float dz = __fsub_rn(cz, Z[c]);
            float d2 = __fadd_rn(__fadd_rn(__fmul_rn(dx, dx), __fmul_rn(dy, dy)),
                                 __fmul_rn(dz, dz));
            in[c] = d2 < R2;
        }
        #pragma unroll
        for (int c = 0; c < CHUNKS; ++c) {
            unsigned long long bal = __ballot(in[c]);
            if (bal) {
                int rank = __popcll(bal & lmask);
                int slot = cnt + rank;
                if (in[c] && slot < NS) {
                    s_gx[w][slot] = X[c]; s_gy[w][slot] = Y[c]; s_gz[w][slot] = Z[c];
                }
                cnt += __popcll(bal);
            }
        }
        if (cnt >= NS) break;
    }
    __syncthreads();

    int found = cnt < NS ? cnt : NS;
    float p0x, p0y, p0z;
    if (found == 0) { p0x = xb[0]; p0y = xb[1]; p0z = xb[2]; }
    else            { p0x = s_gx[w][0]; p0y = s_gy[w][0]; p0z = s_gz[w][0]; }
    if (lane < NS && lane >= found) {
        s_gx[w][lane] = p0x; s_gy[w][lane] = p0y; s_gz[w][lane] = p0z;
    }
    __syncthreads();

    #pragma unroll
    for (int t = 0; t < 16; ++t) {
        int e = t * 64 + lane;
        int di = e >> 5, dj = e & 31;
        float dx = __fsub_rn(s_gx[w][di], s_gx[w][dj]);
        float dy = __fsub_rn(s_gy[w][di], s_gy[w][dj]);
        float dz = __fsub_rn(s_gz[w][di], s_gz[w][dj]);
        s_dis[w][di][dj] =
            sqrtf(__fadd_rn(__fadd_rn(__fmul_rn(dx, dx), __fmul_rn(dy, dy)), __fmul_rn(dz, dz)));
    }
    __syncthreads();

    {
        int i = lane & 31;
        float r[8];
        #pragma unroll
        for (int t = 0; t < 8; ++t) {
            r[t] = __fadd_rn(__fadd_rn(__fadd_rn(s_dis[w][i][t], s_dis[w][i][t + 8]),
                                        s_dis[w][i][t + 16]),
                             s_dis[w][i][t + 24]);
        }
        float mv = __fadd_rn(__fadd_rn(__fadd_rn(r[0], r[1]), __fadd_rn(r[2], r[3])),
                             __fadd_rn(__fadd_rn(r[4], r[5]), __fadd_rn(r[6], r[7])));
        int mi = i;
        #pragma unroll
        for (int off = 1; off < 64; off <<= 1) {
            float ov = __shfl_xor(mv, off);
            int oi = __shfl_xor(mi, off);
            if (ov > mv || (ov == mv && oi < mi)) { mv = ov; mi = oi; }
        }
        float tx = s_gx[w][mi], ty = s_gy[w][mi], tz = s_gz[w][mi];
        float ux = cy * tz - cz * ty, uy = cz * tx - cx * tz, uz = cx * ty - cy * tx;
        float vx = uy * cz - uz * cy, vy = uz * cx - ux * cz, vz = ux * cy - uy * cx;
        float vn = fmaxf(sqrtf(vx * vx + vy * vy + vz * vz), 1e-37f);
        float tnx = vx / vn, tny = vy / vn, tnz = vz / vn;
        float nr = sqrtf(cx * cx + cy * cy + cz * cz);
        float dn = nr + 1e-8f;
        float nnx = cx / dn, nny = cy / dn, nnz = cz / dn;
        int j = lane & 31;
        float gx = s_gx[w][j], gy = s_gy[w][j], gz = s_gz[w][j];
        float ax = cy * gz - cz * gy, ay = cz * gx - cx * gz, az = cx * gy - cy * gx;
        float px = ay * cz - az * cy, py = az * cx - ax * cz, pz = ax * cy - ay * cx;
        float pn = fmaxf(sqrtf(px * px + py * py + pz * pz), 1e-37f);
        px /= pn; py /= pn; pz /= pn;
        float qx = py * tnz - pz * tny;
        float qy = pz * tnx - px * tnz;
        float qz = px * tny - py * tnx;
        float sinv = qx * nnx + qy * nny + qz * nnz;
        float gr = sqrtf(gx * gx + gy * gy + gz * gz);
        const size_t rowstride = (size_t)MM * NS;
        const size_t obase = (((size_t)b * 33) * MM + m) * NS + j;
        if (lane < NS) out[obase + 32 * rowstride] = gr;
        float v[NS];
        #pragma unroll
        for (int ii = 0; ii < NS; ++ii) v[ii] = s_dis[w][ii][j];
        #pragma unroll
        for (int k = 2; k <= NS; k <<= 1) {
            #pragma unroll
            for (int jj = k >> 1; jj > 0; jj >>= 1) {
                #pragma unroll
                for (int ii = 0; ii < NS; ++ii) {
                    int ll = ii ^ jj;
                    if (ll > ii) {
                        bool up = ((ii & k) == 0);
                        float a = v[ii], c2 = v[ll];
                        bool sw = up ? (a > c2) : (a < c2);
                        if (sw) { v[ii] = c2; v[ll] = a; }
                    }
                }
            }
        }
        if (lane < NS) {
            #pragma unroll
            for (int ii = 0; ii < NS; ++ii)
                out[obase + (size_t)ii * rowstride] = v[ii] * sinv;
        }
    }
}

extern "C" void kernel_launch(void* const* d_in, const int* in_sizes, int n_in,
                              void* d_out, int out_size, void* d_ws, size_t ws_size,
                              hipStream_t stream) {
    (void)in_sizes; (void)n_in; (void)out_size;
    const float* xyz = (const float*)d_in[0];
    const float* nxyz = (const float*)d_in[1];
    float* out = (float*)d_out;

    if (d_ws != nullptr && ws_size >= WS_NEED) {
        char* ws = (char*)d_ws;
        int* off = (int*)ws;
        int* cur = (int*)(ws + WS_CUR_OFF);
        int* cnt = (int*)(ws + WS_CNT_OFF);
        float4* pts = (float4*)(ws + WS_PTS_OFF);

        hipMemsetAsync(cnt, 0, 32 * 1024, stream);
        k_count<<<(BB * NN) / 256, 256, 0, stream>>>(xyz, cnt);
        k_scan<<<BB, 256, 0, stream>>>(cnt, off, cur);
        k_scatter<<<(BB * NN) / 256, 256, 0, stream>>>(xyz, cur, pts);
        qgr_grid_kernel<<<(BB * MM) / 8, 256, 0, stream>>>(xyz, nxyz, off, pts, out);
    } else {
        qgr_kernel<<<(BB * MM) / 4, 256, 0, stream>>>(xyz, nxyz, out);
    }
}